// Round 21
// baseline (277.195 us; speedup 1.0000x reference)
//
#include <hip/hip_runtime.h>
#include <hip/hip_bf16.h>

typedef unsigned short u16;
typedef unsigned int   u32;
using bf16x8 = __attribute__((ext_vector_type(8))) short;
using f32x4  = __attribute__((ext_vector_type(4))) float;
using f32x16 = __attribute__((ext_vector_type(16))) float;

#define AS1 __attribute__((address_space(1)))
#define AS3 __attribute__((address_space(3)))

static constexpr int S_   = 1024;
static constexpr int D_   = 4096;
static constexpr int H_   = 32;
static constexpr int KVH_ = 8;
static constexpr int HD_  = 128;
static constexpr int NQKV = H_*HD_ + 2*KVH_*HD_;   // 6144

__device__ __forceinline__ u16 f2bf(float f) {
  union { float f; u32 u; } v; v.f = f;
  u32 r = v.u + 0x7FFFu + ((v.u >> 16) & 1u);      // RTNE
  return (u16)(r >> 16);
}

// ==== ONE preprocessing launch: x-convert || weight transposes || RoPE tables ====
__global__ __launch_bounds__(256) void k_prep(
    const float* __restrict__ x, u16* __restrict__ xb,
    const float* __restrict__ Wq, const float* __restrict__ Wk,
    const float* __restrict__ Wv, const float* __restrict__ Wo,
    u16* __restrict__ WB, u16* __restrict__ WoT,
    const int* __restrict__ sidx, float* __restrict__ cosd, float* __restrict__ sind) {
  constexpr int K = 4096;
  __shared__ float t[64][65];
  int bid = blockIdx.x, tid = threadIdx.x;
  if (bid < 8192) {                                // ---- x f32 -> bf16 ----
    int i = bid * 256 + tid;
    float4 v = ((const float4*)x)[i];
    ushort4 o;
    o.x = f2bf(v.x); o.y = f2bf(v.y); o.z = f2bf(v.z); o.w = f2bf(v.w);
    ((ushort4*)xb)[i] = o;
    return;
  }
  if (bid >= 18432) {                              // ---- RoPE tables ----
    int i = (bid - 18432) * 256 + tid;
    int s = i >> 6, d = i & 63;
    float pos  = (float)sidx[s];
    float invf = expf(-0.21586735246819178f * (float)d);
    float ph   = pos * invf;
    cosd[i] = cosf(ph);
    sind[i] = sinf(ph);
    return;
  }
  // ---- weight transpose, 64x64 tile; Q/K pair-interleaved column perm ----
  int id = bid - 8192;
  const float* src; u16* dst; int N, tx, ty, perm;
  if (id < 4096)      { src = Wq; dst = WB;                        N = 4096; tx = id & 63; ty = id >> 6; perm = 1; }
  else if (id < 5120) { id -= 4096; src = Wk; dst = WB + (size_t)4096*K; N = 1024; tx = id & 15; ty = id >> 4; perm = 1; }
  else if (id < 6144) { id -= 5120; src = Wv; dst = WB + (size_t)5120*K; N = 1024; tx = id & 15; ty = id >> 4; perm = 0; }
  else                { id -= 6144; src = Wo; dst = WoT;           N = 4096; tx = id & 63; ty = id >> 6; perm = 0; }
  int k0 = ty * 64, n0 = tx * 64;
  int srcb[4];
#pragma unroll
  for (int g = 0; g < 4; ++g) {
    int np = n0 + g*16;
    if (perm) {
      int f = (np >> 4) & 7, m = f >> 1;
      srcb[g] = (np & ~127) + ((f & 1) ? 64 + m*16 : m*16);
    } else srcb[g] = np;
  }
  int lr = tid >> 4;
  int lc = (tid & 15) * 4;
  int scol = srcb[lc >> 4] + (lc & 15);
#pragma unroll
  for (int i = 0; i < 4; ++i) {
    float4 v = *(const float4*)&src[(size_t)(k0 + lr + i*16) * N + scol];
    t[lc+0][lr + i*16] = v.x;
    t[lc+1][lr + i*16] = v.y;
    t[lc+2][lr + i*16] = v.z;
    t[lc+3][lr + i*16] = v.w;
  }
  __syncthreads();
  int wn = tid >> 3;
  int wk = (tid & 7) * 8;
#pragma unroll
  for (int i = 0; i < 2; ++i) {
    const float* row = &t[wn + i*32][wk];
    ushort4 a, b;
    a.x = f2bf(row[0]); a.y = f2bf(row[1]); a.z = f2bf(row[2]); a.w = f2bf(row[3]);
    b.x = f2bf(row[4]); b.y = f2bf(row[5]); b.z = f2bf(row[6]); b.w = f2bf(row[7]);
    u16* o = &dst[(size_t)(n0 + wn + i*32) * K + k0 + wk];
    *(ushort4*)o = a;
    *(ushort4*)(o + 4) = b;
  }
}

#define BAR   __builtin_amdgcn_s_barrier()
#define SCHB  __builtin_amdgcn_sched_barrier(0)

// ==== QKV GEMM: BM=128 BN=192, 4 waves (2Mx2N, wave 64x96), 2 BLOCKS/CU ====
// Grid 16x32 = 512 = exactly 2/CU; LDS 80 KB x2 = full 160 KB. Two independent
// barrier domains per CU -> LDS-read and MFMA pipes overlap across blocks.
// N-major per-XCD decode: per XCD 16 m x 4 n-panels (B 6 MB, L3-absorbed).
// Round-15-verified counted-lgkm loop; VT-direct V epilogue (round-20 verified).
__global__ __launch_bounds__(256, 2) void k_gemmq(
    const u16* __restrict__ A, const u16* __restrict__ Bt,
    const float* __restrict__ bq, const float* __restrict__ bk,
    const float* __restrict__ bv,
    const float* __restrict__ cosd, const float* __restrict__ sind,
    u16* __restrict__ qb, u16* __restrict__ kb, u16* __restrict__ VT)
{
  constexpr int K = 4096;
  constexpr int ABYT = 128*128, BBYT = 192*128, STEP = ABYT+BBYT;  // 40 KB
  __shared__ __align__(16) char lds[2*STEP];       // 80 KB

  const int cpx = (int)gridDim.x >> 3;             // 64
  const int wkid = ((int)blockIdx.x & 7)*cpx + ((int)blockIdx.x >> 3);
  const int m0 = (wkid & 15) * 128, n0 = (wkid >> 4) * 192;  // n-major per XCD
  const int tid = threadIdx.x, w = tid>>6, lane = tid&63;
  const int l15 = lane&15, l4 = lane>>4;
  const int wr = w>>1, wc = w&1;                   // 2M x 2N, wave 64x96
  const int row0 = tid>>3;                         // 0..31 (32-row chunks)
  const int ss = (tid&7) ^ (row0&7);
  const int NK = K >> 6;                           // 64

  f32x4 acc[4][6];
#pragma unroll
  for (int i = 0; i < 4; ++i)
#pragma unroll
    for (int j = 0; j < 6; ++j) acc[i][j] = (f32x4){0.f,0.f,0.f,0.f};

  bf16x8 af[2][2][2];
  bf16x8 bfr[2][3][2];

#define QCHUNK(kt_, part_, r0c_)                                              \
  __builtin_amdgcn_global_load_lds(                                           \
    (AS1 void*)(((part_) ? Bt + (size_t)(n0 + (r0c_) + row0)*K                \
                         : A  + (size_t)(m0 + (r0c_) + row0)*K)               \
                + (size_t)(kt_)*64 + ss*8),                                   \
    (AS3 void*)(lds + ((kt_)&1)*STEP + (part_)*ABYT + (r0c_)*128 + w*1024),   \
    16, 0, 0)

#define QSTAGE_A(kt_)  { QCHUNK(kt_,0,0); QCHUNK(kt_,0,32); QCHUNK(kt_,0,64); QCHUNK(kt_,0,96); }
#define QSTAGE_B(kt_)  { QCHUNK(kt_,1,0); QCHUNK(kt_,1,32); QCHUNK(kt_,1,64); \
                         QCHUNK(kt_,1,96); QCHUNK(kt_,1,128); QCHUNK(kt_,1,160); }

#define QR_A(mh_, lA_)                                                        \
  _Pragma("unroll") for (int i2 = 0; i2 < 2; ++i2)                            \
  _Pragma("unroll") for (int kk = 0; kk < 2; ++kk) {                          \
    int row = wr*64 + ((mh_)*2 + i2)*16 + l15;                                \
    af[mh_][i2][kk] = *(const bf16x8*)((lA_) + row*128 + (((kk*4+l4) ^ (row&7)) << 4)); }

#define QR_B(nh_, lB_)                                                        \
  _Pragma("unroll") for (int jj = 0; jj < 3; ++jj)                            \
  _Pragma("unroll") for (int kk = 0; kk < 2; ++kk) {                          \
    int row = wc*96 + ((nh_)*3 + jj)*16 + l15;                                \
    bfr[nh_][jj][kk] = *(const bf16x8*)((lB_) + row*128 + (((kk*4+l4) ^ (row&7)) << 4)); }

#define QMFMA(mh_, nh_)                                                       \
  __builtin_amdgcn_s_setprio(1);                                              \
  _Pragma("unroll") for (int i2 = 0; i2 < 2; ++i2)                            \
  _Pragma("unroll") for (int jj = 0; jj < 3; ++jj)                            \
  _Pragma("unroll") for (int kk = 0; kk < 2; ++kk)                            \
    acc[(mh_)*2+i2][(nh_)*3+jj] = __builtin_amdgcn_mfma_f32_16x16x32_bf16(    \
        af[mh_][i2][kk], bfr[nh_][jj][kk], acc[(mh_)*2+i2][(nh_)*3+jj], 0, 0, 0); \
  __builtin_amdgcn_s_setprio(0);

  // prologue: stage tiles 0,1 (10 each); wait tile0; read its A0,B0
  QSTAGE_A(0); QSTAGE_B(0);
  QSTAGE_A(1); QSTAGE_B(1);
  asm volatile("s_waitcnt vmcnt(10)" ::: "memory");
  BAR; SCHB;
  {
    const char* lA0 = lds;
    const char* lB0 = lds + ABYT;
    QR_A(0, lA0); QR_B(0, lB0);
  }

  for (int kt = 0; kt < NK; ++kt) {
    const char* lA = lds + (kt&1)*STEP;
    const char* lB = lA + ABYT;
    // ph0: issue B1(6); drain A0,B0 (leave 6); MFMA(0,0)
    QR_B(1, lB);
    asm volatile("s_waitcnt lgkmcnt(6)" ::: "memory");
    SCHB;
    QMFMA(0,0);
    // ph1: issue A1(4); drain B1 (leave 4); barrier; stage B(kt+2); MFMA(0,1)
    QR_A(1, lA);
    asm volatile("s_waitcnt lgkmcnt(4)" ::: "memory");
    BAR; SCHB;
    if (kt+2 < NK) QSTAGE_B(kt+2);
    QMFMA(0,1);
    // ph2: drain A1; barrier; stage A(kt+2); MFMA(1,0)
    asm volatile("s_waitcnt lgkmcnt(0)" ::: "memory");
    BAR; SCHB;
    if (kt+2 < NK) QSTAGE_A(kt+2);
    QMFMA(1,0);
    // ph3: tile kt+1 resident (vmcnt 10 = kt+2's loads); barrier; read A0,B0; MFMA(1,1)
    if (kt+1 < NK) {
      if (kt+2 < NK) asm volatile("s_waitcnt vmcnt(10)" ::: "memory");
      else           asm volatile("s_waitcnt vmcnt(0)" ::: "memory");
      BAR; SCHB;
      const char* lAn = lds + ((kt+1)&1)*STEP;
      const char* lBn = lAn + ABYT;
      QR_A(0, lAn); QR_B(0, lBn);
      SCHB;
    }
    QMFMA(1,1);
  }
#undef QCHUNK
#undef QSTAGE_A
#undef QSTAGE_B
#undef QR_A
#undef QR_B
#undef QMFMA

  // ---- fused epilogue: Q/K with RoPE; V written TRANSPOSED into VT[b][g][d][s] ----
  const int cb16 = (n0 + wc*96) >> 4;
#pragma unroll
  for (int p = 0; p < 3; ++p) {
    int g0 = cb16 + 2*p;
    if (g0 < 320) {
      bool isQ = (g0 < 256);
      int gs = isQ ? g0 : g0 - 256;
      int h = gs >> 3, m = (gs & 7) >> 1;
      int dlo = m*16 + l15;
      const float* bias = isQ ? bq : bk;
      u16* dst = isQ ? qb : kb;
      int nheads = isQ ? H_ : KVH_;
      float scale = isQ ? 0.08838834764831845f : 1.0f;
      float b_lo = bias[h*128 + dlo];
      float b_hi = bias[h*128 + 64 + dlo];
#pragma unroll
      for (int i = 0; i < 4; ++i)
#pragma unroll
        for (int r = 0; r < 4; ++r) {
          int sr = m0 + wr*64 + i*16 + l4*4 + r;
          int b_ = sr >> 10, s_ = sr & 1023;
          float cs = cosd[s_*64 + dlo], sn = sind[s_*64 + dlo];
          float lo = acc[i][2*p][r]   + b_lo;
          float hi = acc[i][2*p+1][r] + b_hi;
          size_t obase = (((size_t)b_*nheads + h)*S_ + s_)*(size_t)HD_;
          dst[obase + dlo]      = f2bf((lo*cs - hi*sn) * scale);
          dst[obase + 64 + dlo] = f2bf((hi*cs + lo*sn) * scale);
        }
    } else {                                       // V: write transposed
#pragma unroll
      for (int q = 0; q < 2; ++q) {
        int gv = g0 + q - 320;
        int h = gv >> 3, d = (gv & 7)*16 + l15;
        float bbv = bv[h*128 + d];
#pragma unroll
        for (int i = 0; i < 4; ++i)
#pragma unroll
          for (int r = 0; r < 4; ++r) {
            int sr = m0 + wr*64 + i*16 + l4*4 + r;
            int b_ = sr >> 10, s_ = sr & 1023;
            VT[(((size_t)b_*KVH_ + h)*(size_t)HD_ + d)*S_ + s_] = f2bf(acc[i][2*p+q][r] + bbv);
          }
      }
    }
  }
}

// ==== Out-projection GEMM: BM=256 BN=128, 32x32x16 MFMA, 8 waves 4Mx2N ====
__global__ __launch_bounds__(512, 2) void k_gemmo(
    const u16* __restrict__ A, const u16* __restrict__ Bt,
    float* __restrict__ C, int N, int K)
{
  constexpr int ABYT = 256*128, BBYT = 128*128, STEP = ABYT+BBYT;  // 48 KB
  __shared__ __align__(16) char lds[2*STEP];       // 96 KB

  const int cpx = (int)gridDim.x >> 3;             // 32
  const int wkid = ((int)blockIdx.x & 7)*cpx + ((int)blockIdx.x >> 3);
  const int m0 = (wkid & 7) * 256, n0 = (wkid >> 3) * 128;   // n-major per XCD
  const int tid = threadIdx.x, w = tid>>6, lane = tid&63;
  const int l31 = lane & 31, lh = lane >> 5;
  const int wr = w>>1, wc = w&1;                   // 4M x 2N, wave 64x64
  const int row0 = tid>>3;
  const int ss = (tid&7) ^ (row0&7);
  const int NK = K >> 6;

  f32x16 acc00 = {}, acc01 = {}, acc10 = {}, acc11 = {};

  bf16x8 af[2][4];
  bf16x8 bfr[2][4];

#define OCHUNK(kt_, part_, r0c_)                                              \
  __builtin_amdgcn_global_load_lds(                                           \
    (AS1 void*)(((part_) ? Bt + (size_t)(n0 + (r0c_) + row0)*K                \
                         : A  + (size_t)(m0 + (r0c_) + row0)*K)               \
                + (size_t)(kt_)*64 + ss*8),                                   \
    (AS3 void*)(lds + ((kt_)&1)*STEP + (part_)*ABYT + (r0c_)*128 + w*1024),   \
    16, 0, 0)

#define OSTAGE_A(kt_)  { OCHUNK(kt_,0,0); OCHUNK(kt_,0,64); OCHUNK(kt_,0,128); OCHUNK(kt_,0,192); }
#define OSTAGE_B(kt_)  { OCHUNK(kt_,1,0); OCHUNK(kt_,1,64); }

#define OR_A(mh_, lA_)                                                        \
  _Pragma("unroll") for (int st = 0; st < 4; ++st) {                          \
    int row = wr*64 + (mh_)*32 + l31;                                         \
    af[mh_][st] = *(const bf16x8*)((lA_) + row*128 + ((((st*2)+lh) ^ (row&7)) << 4)); }

#define OR_B(nh_, lB_)                                                        \
  _Pragma("unroll") for (int st = 0; st < 4; ++st) {                          \
    int row = wc*64 + (nh_)*32 + l31;                                         \
    bfr[nh_][st] = *(const bf16x8*)((lB_) + row*128 + ((((st*2)+lh) ^ (row&7)) << 4)); }

#define OMFMA(mh_, nh_, accv_)                                                \
  __builtin_amdgcn_s_setprio(1);                                              \
  _Pragma("unroll") for (int st = 0; st < 4; ++st)                            \
    accv_ = __builtin_amdgcn_mfma_f32_32x32x16_bf16(af[mh_][st], bfr[nh_][st], accv_, 0, 0, 0); \
  __builtin_amdgcn_s_setprio(0);

  OSTAGE_A(0); OSTAGE_B(0);
  OSTAGE_A(1); OSTAGE_B(1);
  asm volatile("s_waitcnt vmcnt(6)" ::: "memory");
  BAR; SCHB;
  {
    const char* lA0 = lds;
    const char* lB0 = lds + ABYT;
    OR_A(0, lA0); OR_B(0, lB0);
  }

  for (int kt = 0; kt < NK; ++kt) {
    const char* lA = lds + (kt&1)*STEP;
    const char* lB = lA + ABYT;
    OR_B(1, lB);
    asm volatile("s_waitcnt lgkmcnt(4)" ::: "memory");
    SCHB;
    OMFMA(0,0, acc00);
    OR_A(1, lA);
    asm volatile("s_waitcnt lgkmcnt(4)" ::: "memory");
    BAR; SCHB;
    if (kt+2 < NK) OSTAGE_B(kt+2);
    OMFMA(0,1, acc01);
    asm volatile("s_waitcnt lgkmcnt(0)" ::: "memory");
    BAR; SCHB;
    if (kt+2 < NK) OSTAGE_A(kt+2);
    OMFMA(1,0, acc10);
    if (kt+1 < NK) {
      if (kt+2 < NK) asm volatile("s_waitcnt vmcnt(6)" ::: "memory");
      else           asm volatile("s_waitcnt vmcnt(0)" ::: "memory");
      BAR; SCHB;
      const char* lAn = lds + ((kt+1)&1)*STEP;
      const char* lBn = lAn + ABYT;
      OR_A(0, lAn); OR_B(0, lBn);
      SCHB;
    }
    OMFMA(1,1, acc11);
  }
#undef OCHUNK
#undef OSTAGE_A
#undef OSTAGE_B
#undef OR_A
#undef OR_B
#undef OMFMA

#define OWRITE(mh_, nh_, accv_)                                               \
  _Pragma("unroll") for (int r = 0; r < 16; ++r) {                            \
    int row = m0 + wr*64 + (mh_)*32 + (r & 3) + 8*(r >> 2) + 4*lh;            \
    int col = n0 + wc*64 + (nh_)*32 + l31;                                    \
    C[(size_t)row * N + col] = accv_[r]; }
  OWRITE(0,0, acc00); OWRITE(0,1, acc01); OWRITE(1,0, acc10); OWRITE(1,1, acc11);
#undef OWRITE
}

// ---------------- causal GQA flash attention: block-cooperative LDS-staged K/V -------
__global__ __launch_bounds__(256, 4) void k_attn(
    const u16* __restrict__ Q, const u16* __restrict__ Kc,
    const u16* __restrict__ Vt, u16* __restrict__ AO)
{
  __shared__ __align__(16) char Kls[2][16384];
  __shared__ __align__(16) char Vls[2][16384];
  __shared__ u16 Pl[4][1024];

  int id = blockIdx.x;
  int slot = id >> 3;
  int bg   = (id & 7)*2 + (slot & 1);
  int rem  = slot >> 1;
  int h_in = rem & 3, bx = rem >> 2;
  int b = bg >> 3, g = bg & 7, h = g*4 + h_in;
  int tA = bx, tB = 15 - bx;

  int tid = threadIdx.x, w = tid >> 6, lane = tid & 63;
  int l15 = lane & 15, l4 = lane >> 4;
  const u16* Qh = Q  + ((size_t)b*H_   + h) * S_ * HD_;
  const u16* Kp = Kc + ((size_t)b*KVH_ + g) * S_ * HD_;
  const u16* Vp = Vt + ((size_t)b*KVH_ + g) * (size_t)HD_ * S_;
  u16* AOh = AO + ((size_t)b*S_) * (H_*HD_) + h*HD_;
  char* Pw = (char*)&Pl[w][0];

  int kOff[4], vOff[4];
#pragma unroll
  for (int c = 0; c < 4; ++c) {
    int ci = c*256 + tid;
    int krow = ci >> 4, ks = ci & 15;
    kOff[c] = krow * HD_ + ((ks & 8) | ((ks & 7) ^ (krow & 7))) * 8;
    int vrow = ci >> 3, vs = ci & 7;
    vOff[c] = vrow * S_ + (vs ^ (vrow & 7)) * 8;
  }

#define ASTAGE(kv_, bb_) {                                                    \
    const u16* ks_ = Kp + (size_t)(kv_) * 64 * HD_;                           \
    const u16* vs_ = Vp + (size_t)(kv_) * 64;                                 \
    _Pragma("unroll") for (int c = 0; c < 4; ++c) {                           \
      __builtin_amdgcn_global_load_lds((AS1 void*)(ks_ + kOff[c]),            \
          (AS3 void*)(&Kls[bb_][0] + c*4096 + w*1024), 16, 0, 0);             \
      __builtin_amdgcn_global_load_lds((AS1 void*)(vs_ + vOff[c]),            \
          (AS3 void*)(&Vls[bb_][0] + c*4096 + w*1024), 16, 0, 0); } }

  bf16x8 qf[4];
#pragma unroll
  for (int kc = 0; kc < 4; ++kc)
    qf[kc] = *(const bf16x8*)(Qh + (size_t)(tA*64 + w*16 + l15)*HD_ + kc*32 + l4*8);

  f32x4 o[8];
#pragma unroll
  for (int n = 0; n < 8; ++n) o[n] = (f32x4){0.f,0.f,0.f,0.f};
  float mrow[4] = {-3e38f,-3e38f,-3e38f,-3e38f};
  float lrow[4] = {0.f,0.f,0.f,0.f};

  ASTAGE(0, 0);
  asm volatile("s_waitcnt vmcnt(0)" ::: "memory");
  __builtin_amdgcn_s_barrier();

  const int NIT = tA + tB + 2;
  int buf = 0;
  for (int it = 0; it < NIT; ++it) {
    bool phA = (it <= tA);
    int kv = phA ? it : it - tA - 1;
    int qt = phA ? tA : tB;
    if (it + 1 < NIT) {
      int kvn = (it + 1 <= tA) ? it + 1 : it - tA;
      ASTAGE(kvn, buf ^ 1);
    }
    const char* Ksb = &Kls[buf][0];
    const char* Vsb = &Vls[buf][0];

    f32x4 sc[4];
    __builtin_amdgcn_s_setprio(1);
#pragma unroll
    for (int ct = 0; ct < 4; ++ct) {
      f32x4 s4 = (f32x4){0.f,0.f,0.f,0.f};
#pragma unroll
      for (int kc = 0; kc < 4; ++kc) {
        int row = ct*16 + l15, s = kc*4 + l4;
        bf16x8 kf = *(const bf16x8*)(Ksb + row*256 + ((((s & 7) ^ (row & 7)) | (s & 8)) << 4));
        s4 = __builtin_amdgcn_mfma_f32_16x16x32_bf16(qf[kc], kf, s4, 0, 0, 0);
      }
      sc[ct] = s4;
    }
    __builtin_amdgcn_s_setprio(0);

    if (kv == qt) {
      int qrow0 = qt*64 + w*16;
#pragma unroll
      for (int ct = 0; ct < 4; ++ct)
#pragma unroll
        for (int r = 0; r < 4; ++r) {
          int col = kv*64 + ct*16 + l15;
          if (col > qrow0 + l4*4 + r) sc[ct][r] = -1e9f;
        }
    }

    float f[4];
#pragma unroll
    for (int r = 0; r < 4; ++r) {
      float mx = fmaxf(fmaxf(sc[0][r], sc[1][r]), fmaxf(sc[2][r], sc[3][r]));
      mx = fmaxf(mx, __shfl_xor(mx, 1));
      mx = fmaxf(mx, __shfl_xor(mx, 2));
      mx = fmaxf(mx, __shfl_xor(mx, 4));
      mx = fmaxf(mx, __shfl_xor(mx, 8));
      float nm = fmaxf(mrow[r], mx);
      f[r] = __expf(mrow[r] - nm);
      mrow[r] = nm;
    }
    float rs[4] = {0.f,0.f,0.f,0.f};
#pragma unroll
    for (int ct = 0; ct < 4; ++ct)
#pragma unroll
      for (int r = 0; r < 4; ++r) {
        float p = __expf(sc[ct][r] - mrow[r]);
        rs[r] += p;
        int row = l4*4 + r, col = ct*16 + l15;
        int byte = row*128 + (((col >> 3) ^ (row & 7)) << 4) + (col & 7)*2;
        *(u16*)(Pw + byte) = f2bf(p);
      }
#pragma unroll
    for (int r = 0; r < 4; ++r) {
      float sum = rs[r];
      sum += __shfl_xor(sum, 1);
      sum += __shfl_xor(sum, 2);
      sum += __shfl_xor(sum, 4);
      sum += __shfl_xor(sum, 8);
      lrow[r] = lrow[r]*f[r] + sum;
    }
#pragma unroll
    for (int n = 0; n < 8; ++n)
#pragma unroll
      for (int r = 0; r < 4; ++r) o[n][r] *= f[r];

    __builtin_amdgcn_s_setprio(1);
#pragma unroll
    for (int kk = 0; kk < 2; ++kk) {
      int pbyte = l15*128 + (((kk*4 + l4) ^ (l15 & 7)) << 4);
      bf16x8 pf = *(const bf16x8*)(Pw + pbyte);
#pragma unroll
      for (int n = 0; n < 8; ++n) {
        int vrow = n*16 + l15, s = kk*4 + l4;
        bf16x8 vf = *(const bf16x8*)(Vsb + vrow*128 + ((s ^ (vrow & 7)) << 4));
        o[n] = __builtin_amdgcn_mfma_f32_16x16x32_bf16(pf, vf, o[n], 0, 0, 0);
      }
    }
    __builtin_amdgcn_s_setprio(0);

    if (it == tA) {
#pragma unroll
      for (int n = 0; n < 8; ++n)
#pragma unroll
        for (int r = 0; r < 4; ++r) {
          int srow = tA*64 + w*16 + l4*4 + r;
          AOh[(size_t)srow * (H_*HD_) + n*16 + l15] = f2bf(o[n][r] / lrow[r]);
        }
#pragma unroll
      for (int n = 0; n < 8; ++n) o[n] = (f32x4){0.f,0.f,0.f,0.f};
#pragma unroll
      for (int r = 0; r < 4; ++r) { mrow[r] = -3e38f; lrow[r] = 0.f; }
#pragma unroll
      for (int kc = 0; kc < 4; ++kc)
        qf[kc] = *(const bf16x8*)(Qh + (size_t)(tB*64 + w*16 + l15)*HD_ + kc*32 + l4*8);
    }

    asm volatile("s_waitcnt vmcnt(0)" ::: "memory");
    __builtin_amdgcn_s_barrier();
    buf ^= 1;
  }
#undef ASTAGE

#pragma unroll
  for (int n = 0; n < 8; ++n)
#pragma unroll
    for (int r = 0; r < 4; ++r) {
      int srow = tB*64 + w*16 + l4*4 + r;
      AOh[(size_t)srow * (H_*HD_) + n*16 + l15] = f2bf(o[n][r] / lrow[r]);
    }
}

extern "C" void kernel_launch(void* const* d_in, const int* in_sizes, int n_in,
                              void* d_out, int out_size, void* d_ws, size_t ws_size,
                              hipStream_t stream) {
  (void)in_sizes; (void)n_in; (void)out_size; (void)ws_size;
  const float* x   = (const float*)d_in[0];
  const int*   sid = (const int*)  d_in[1];
  // d_in[2] = cache (dead), d_in[3] = mask (dead: causal re-derived)
  const float* Wq  = (const float*)d_in[4];
  const float* bq  = (const float*)d_in[5];
  const float* Wk  = (const float*)d_in[6];
  const float* bk  = (const float*)d_in[7];
  const float* Wv  = (const float*)d_in[8];
  const float* bv  = (const float*)d_in[9];
  const float* Wo  = (const float*)d_in[10];
  float* out = (float*)d_out;

  char* ws = (char*)d_ws;
  u16*   xb   = (u16*)  (ws);                    // 16 MB (aliased by AO later)
  u16*   WB   = (u16*)  (ws + 16777216);         // 48 MB  [6144][4096] (Q/K cols permuted)
  u16*   WoT  = (u16*)  (ws + 67108864);         // 32 MB  [4096][4096]
  u16*   qb   = (u16*)  (ws + 150994944);        // 16 MB  [B][H][S][HD]
  u16*   kb   = (u16*)  (ws + 167772160);        //  4 MB  [B][KVH][S][HD]
  u16*   VT   = (u16*)  (ws + 176160768);        //  4 MB  [B][KVH][HD][S]
  float* cosd = (float*)(ws + 180355072);        // 256 KB
  float* sind = (float*)(ws + 180617216);        // 256 KB
  u16*   AO   = xb;                              // attention output reuses xb

  k_prep<<<18688, 256, 0, stream>>>(x, xb, Wq, Wk, Wv, Wo, WB, WoT, sid, cosd, sind);
  k_gemmq<<<512, 256, 0, stream>>>(xb, WB, bq, bk, bv, cosd, sind, qb, kb, VT);
  k_attn<<<512, 256, 0, stream>>>(qb, kb, VT, AO);
  k_gemmo<<<256, 512, 0, stream>>>(AO, WoT, out, 4096, 4096);
}

// Round 22
// 272.897 us; speedup vs baseline: 1.0157x; 1.0157x over previous
//
#include <hip/hip_runtime.h>
#include <hip/hip_bf16.h>

typedef unsigned short u16;
typedef unsigned int   u32;
using bf16x8 = __attribute__((ext_vector_type(8))) short;
using f32x4  = __attribute__((ext_vector_type(4))) float;
using f32x16 = __attribute__((ext_vector_type(16))) float;

#define AS1 __attribute__((address_space(1)))
#define AS3 __attribute__((address_space(3)))

static constexpr int S_   = 1024;
static constexpr int D_   = 4096;
static constexpr int H_   = 32;
static constexpr int KVH_ = 8;
static constexpr int HD_  = 128;
static constexpr int NQKV = H_*HD_ + 2*KVH_*HD_;   // 6144

__device__ __forceinline__ u16 f2bf(float f) {
  union { float f; u32 u; } v; v.f = f;
  u32 r = v.u + 0x7FFFu + ((v.u >> 16) & 1u);      // RTNE
  return (u16)(r >> 16);
}

// ==== ONE preprocessing launch: x-convert || weight transposes || RoPE tables ====
__global__ __launch_bounds__(256) void k_prep(
    const float* __restrict__ x, u16* __restrict__ xb,
    const float* __restrict__ Wq, const float* __restrict__ Wk,
    const float* __restrict__ Wv, const float* __restrict__ Wo,
    u16* __restrict__ WB, u16* __restrict__ WoT,
    const int* __restrict__ sidx, float* __restrict__ cosd, float* __restrict__ sind) {
  constexpr int K = 4096;
  __shared__ float t[64][65];
  int bid = blockIdx.x, tid = threadIdx.x;
  if (bid < 8192) {                                // ---- x f32 -> bf16 ----
    int i = bid * 256 + tid;
    float4 v = ((const float4*)x)[i];
    ushort4 o;
    o.x = f2bf(v.x); o.y = f2bf(v.y); o.z = f2bf(v.z); o.w = f2bf(v.w);
    ((ushort4*)xb)[i] = o;
    return;
  }
  if (bid >= 18432) {                              // ---- RoPE tables ----
    int i = (bid - 18432) * 256 + tid;
    int s = i >> 6, d = i & 63;
    float pos  = (float)sidx[s];
    float invf = expf(-0.21586735246819178f * (float)d);
    float ph   = pos * invf;
    cosd[i] = cosf(ph);
    sind[i] = sinf(ph);
    return;
  }
  // ---- weight transpose, 64x64 tile; Q/K pair-interleaved column perm ----
  int id = bid - 8192;
  const float* src; u16* dst; int N, tx, ty, perm;
  if (id < 4096)      { src = Wq; dst = WB;                        N = 4096; tx = id & 63; ty = id >> 6; perm = 1; }
  else if (id < 5120) { id -= 4096; src = Wk; dst = WB + (size_t)4096*K; N = 1024; tx = id & 15; ty = id >> 4; perm = 1; }
  else if (id < 6144) { id -= 5120; src = Wv; dst = WB + (size_t)5120*K; N = 1024; tx = id & 15; ty = id >> 4; perm = 0; }
  else                { id -= 6144; src = Wo; dst = WoT;           N = 4096; tx = id & 63; ty = id >> 6; perm = 0; }
  int k0 = ty * 64, n0 = tx * 64;
  int srcb[4];
#pragma unroll
  for (int g = 0; g < 4; ++g) {
    int np = n0 + g*16;
    if (perm) {
      int f = (np >> 4) & 7, m = f >> 1;
      srcb[g] = (np & ~127) + ((f & 1) ? 64 + m*16 : m*16);
    } else srcb[g] = np;
  }
  int lr = tid >> 4;
  int lc = (tid & 15) * 4;
  int scol = srcb[lc >> 4] + (lc & 15);
#pragma unroll
  for (int i = 0; i < 4; ++i) {
    float4 v = *(const float4*)&src[(size_t)(k0 + lr + i*16) * N + scol];
    t[lc+0][lr + i*16] = v.x;
    t[lc+1][lr + i*16] = v.y;
    t[lc+2][lr + i*16] = v.z;
    t[lc+3][lr + i*16] = v.w;
  }
  __syncthreads();
  int wn = tid >> 3;
  int wk = (tid & 7) * 8;
#pragma unroll
  for (int i = 0; i < 2; ++i) {
    const float* row = &t[wn + i*32][wk];
    ushort4 a, b;
    a.x = f2bf(row[0]); a.y = f2bf(row[1]); a.z = f2bf(row[2]); a.w = f2bf(row[3]);
    b.x = f2bf(row[4]); b.y = f2bf(row[5]); b.z = f2bf(row[6]); b.w = f2bf(row[7]);
    u16* o = &dst[(size_t)(n0 + wn + i*32) * K + k0 + wk];
    *(ushort4*)o = a;
    *(ushort4*)(o + 4) = b;
  }
}

#define BAR   __builtin_amdgcn_s_barrier()
#define SCHB  __builtin_amdgcn_sched_barrier(0)

// ==== QKV GEMM: BM=256 BN=192, 8 waves (4Mx2N, wave 64x96), grid 256 = 1/CU ====
// N-major per-XCD decode (round-18 best schedule). Epilogue writes V TRANSPOSED
// directly into VT[b][g][d][s].
__global__ __launch_bounds__(512, 2) void k_gemmq(
    const u16* __restrict__ A, const u16* __restrict__ Bt,
    const float* __restrict__ bq, const float* __restrict__ bk,
    const float* __restrict__ bv,
    const float* __restrict__ cosd, const float* __restrict__ sind,
    u16* __restrict__ qb, u16* __restrict__ kb, u16* __restrict__ VT)
{
  constexpr int K = 4096;
  constexpr int ABYT = 256*128, BBYT = 192*128, STEP = ABYT+BBYT;  // 56 KB
  __shared__ __align__(16) char lds[2*STEP];       // 112 KB

  const int cpx = (int)gridDim.x >> 3;             // 32
  const int wkid = ((int)blockIdx.x & 7)*cpx + ((int)blockIdx.x >> 3);
  const int m0 = (wkid & 7) * 256, n0 = (wkid >> 3) * 192;   // n-major per XCD
  const int tid = threadIdx.x, w = tid>>6, lane = tid&63;
  const int l15 = lane&15, l4 = lane>>4;
  const int wr = w>>1, wc = w&1;                   // 4M x 2N, wave 64x96
  const int row0 = tid>>3;                         // 0..63
  const int ss = (tid&7) ^ (row0&7);
  const int NK = K >> 6;                           // 64

  f32x4 acc[4][6];
#pragma unroll
  for (int i = 0; i < 4; ++i)
#pragma unroll
    for (int j = 0; j < 6; ++j) acc[i][j] = (f32x4){0.f,0.f,0.f,0.f};

  bf16x8 af[2][2][2];
  bf16x8 bfr[2][3][2];

#define QCHUNK(kt_, part_, r0c_)                                              \
  __builtin_amdgcn_global_load_lds(                                           \
    (AS1 void*)(((part_) ? Bt + (size_t)(n0 + (r0c_) + row0)*K                \
                         : A  + (size_t)(m0 + (r0c_) + row0)*K)               \
                + (size_t)(kt_)*64 + ss*8),                                   \
    (AS3 void*)(lds + ((kt_)&1)*STEP + (part_)*ABYT + (r0c_)*128 + w*1024),   \
    16, 0, 0)

#define QSTAGE_A(kt_)  { QCHUNK(kt_,0,0); QCHUNK(kt_,0,64); QCHUNK(kt_,0,128); QCHUNK(kt_,0,192); }
#define QSTAGE_B(kt_)  { QCHUNK(kt_,1,0); QCHUNK(kt_,1,64); QCHUNK(kt_,1,128); }

#define QR_A(mh_, lA_)                                                        \
  _Pragma("unroll") for (int i2 = 0; i2 < 2; ++i2)                            \
  _Pragma("unroll") for (int kk = 0; kk < 2; ++kk) {                          \
    int row = wr*64 + ((mh_)*2 + i2)*16 + l15;                                \
    af[mh_][i2][kk] = *(const bf16x8*)((lA_) + row*128 + (((kk*4+l4) ^ (row&7)) << 4)); }

#define QR_B(nh_, lB_)                                                        \
  _Pragma("unroll") for (int jj = 0; jj < 3; ++jj)                            \
  _Pragma("unroll") for (int kk = 0; kk < 2; ++kk) {                          \
    int row = wc*96 + ((nh_)*3 + jj)*16 + l15;                                \
    bfr[nh_][jj][kk] = *(const bf16x8*)((lB_) + row*128 + (((kk*4+l4) ^ (row&7)) << 4)); }

#define QMFMA(mh_, nh_)                                                       \
  __builtin_amdgcn_s_setprio(1);                                              \
  _Pragma("unroll") for (int i2 = 0; i2 < 2; ++i2)                            \
  _Pragma("unroll") for (int jj = 0; jj < 3; ++jj)                            \
  _Pragma("unroll") for (int kk = 0; kk < 2; ++kk)                            \
    acc[(mh_)*2+i2][(nh_)*3+jj] = __builtin_amdgcn_mfma_f32_16x16x32_bf16(    \
        af[mh_][i2][kk], bfr[nh_][jj][kk], acc[(mh_)*2+i2][(nh_)*3+jj], 0, 0, 0); \
  __builtin_amdgcn_s_setprio(0);

  // prologue: stage tiles 0,1 (7 each); wait tile0; read its A0,B0
  QSTAGE_A(0); QSTAGE_B(0);
  QSTAGE_A(1); QSTAGE_B(1);
  asm volatile("s_waitcnt vmcnt(7)" ::: "memory");
  BAR; SCHB;
  {
    const char* lA0 = lds;
    const char* lB0 = lds + ABYT;
    QR_A(0, lA0); QR_B(0, lB0);
  }

  for (int kt = 0; kt < NK; ++kt) {
    const char* lA = lds + (kt&1)*STEP;
    const char* lB = lA + ABYT;
    // ph0: issue B1(6); drain A0,B0 (leave 6); MFMA(0,0)
    QR_B(1, lB);
    asm volatile("s_waitcnt lgkmcnt(6)" ::: "memory");
    SCHB;
    QMFMA(0,0);
    // ph1: issue A1(4); drain B1 (leave 4); barrier; stage B(kt+2); MFMA(0,1)
    QR_A(1, lA);
    asm volatile("s_waitcnt lgkmcnt(4)" ::: "memory");
    BAR; SCHB;
    if (kt+2 < NK) QSTAGE_B(kt+2);
    QMFMA(0,1);
    // ph2: drain A1; barrier; stage A(kt+2); MFMA(1,0)
    asm volatile("s_waitcnt lgkmcnt(0)" ::: "memory");
    BAR; SCHB;
    if (kt+2 < NK) QSTAGE_A(kt+2);
    QMFMA(1,0);
    // ph3: tile kt+1 resident; barrier; read its A0,B0; MFMA(1,1)
    if (kt+1 < NK) {
      if (kt+2 < NK) asm volatile("s_waitcnt vmcnt(7)" ::: "memory");
      else           asm volatile("s_waitcnt vmcnt(0)" ::: "memory");
      BAR; SCHB;
      const char* lAn = lds + ((kt+1)&1)*STEP;
      const char* lBn = lAn + ABYT;
      QR_A(0, lAn); QR_B(0, lBn);
      SCHB;
    }
    QMFMA(1,1);
  }
#undef QCHUNK
#undef QSTAGE_A
#undef QSTAGE_B
#undef QR_A
#undef QR_B
#undef QMFMA

  // ---- fused epilogue: Q/K with RoPE; V written TRANSPOSED into VT[b][g][d][s] ----
  const int cb16 = (n0 + wc*96) >> 4;
#pragma unroll
  for (int p = 0; p < 3; ++p) {
    int g0 = cb16 + 2*p;
    if (g0 < 320) {
      bool isQ = (g0 < 256);
      int gs = isQ ? g0 : g0 - 256;
      int h = gs >> 3, m = (gs & 7) >> 1;
      int dlo = m*16 + l15;
      const float* bias = isQ ? bq : bk;
      u16* dst = isQ ? qb : kb;
      int nheads = isQ ? H_ : KVH_;
      float scale = isQ ? 0.08838834764831845f : 1.0f;
      float b_lo = bias[h*128 + dlo];
      float b_hi = bias[h*128 + 64 + dlo];
#pragma unroll
      for (int i = 0; i < 4; ++i)
#pragma unroll
        for (int r = 0; r < 4; ++r) {
          int sr = m0 + wr*64 + i*16 + l4*4 + r;
          int b_ = sr >> 10, s_ = sr & 1023;
          float cs = cosd[s_*64 + dlo], sn = sind[s_*64 + dlo];
          float lo = acc[i][2*p][r]   + b_lo;
          float hi = acc[i][2*p+1][r] + b_hi;
          size_t obase = (((size_t)b_*nheads + h)*S_ + s_)*(size_t)HD_;
          dst[obase + dlo]      = f2bf((lo*cs - hi*sn) * scale);
          dst[obase + 64 + dlo] = f2bf((hi*cs + lo*sn) * scale);
        }
    } else {                                       // V: write transposed
#pragma unroll
      for (int q = 0; q < 2; ++q) {
        int gv = g0 + q - 320;
        int h = gv >> 3, d = (gv & 7)*16 + l15;
        float bbv = bv[h*128 + d];
#pragma unroll
        for (int i = 0; i < 4; ++i)
#pragma unroll
          for (int r = 0; r < 4; ++r) {
            int sr = m0 + wr*64 + i*16 + l4*4 + r;
            int b_ = sr >> 10, s_ = sr & 1023;
            VT[(((size_t)b_*KVH_ + h)*(size_t)HD_ + d)*S_ + s_] = f2bf(acc[i][2*p+q][r] + bbv);
          }
      }
    }
  }
}

// ==== Out-projection GEMM: BM=256 BN=128, 32x32x16 MFMA, 8 waves 4Mx2N ====
__global__ __launch_bounds__(512, 2) void k_gemmo(
    const u16* __restrict__ A, const u16* __restrict__ Bt,
    float* __restrict__ C, int N, int K)
{
  constexpr int ABYT = 256*128, BBYT = 128*128, STEP = ABYT+BBYT;  // 48 KB
  __shared__ __align__(16) char lds[2*STEP];       // 96 KB

  const int cpx = (int)gridDim.x >> 3;             // 32
  const int wkid = ((int)blockIdx.x & 7)*cpx + ((int)blockIdx.x >> 3);
  const int m0 = (wkid & 7) * 256, n0 = (wkid >> 3) * 128;   // n-major per XCD
  const int tid = threadIdx.x, w = tid>>6, lane = tid&63;
  const int l31 = lane & 31, lh = lane >> 5;
  const int wr = w>>1, wc = w&1;                   // 4M x 2N, wave 64x64
  const int row0 = tid>>3;
  const int ss = (tid&7) ^ (row0&7);
  const int NK = K >> 6;

  f32x16 acc00 = {}, acc01 = {}, acc10 = {}, acc11 = {};

  bf16x8 af[2][4];
  bf16x8 bfr[2][4];

#define OCHUNK(kt_, part_, r0c_)                                              \
  __builtin_amdgcn_global_load_lds(                                           \
    (AS1 void*)(((part_) ? Bt + (size_t)(n0 + (r0c_) + row0)*K                \
                         : A  + (size_t)(m0 + (r0c_) + row0)*K)               \
                + (size_t)(kt_)*64 + ss*8),                                   \
    (AS3 void*)(lds + ((kt_)&1)*STEP + (part_)*ABYT + (r0c_)*128 + w*1024),   \
    16, 0, 0)

#define OSTAGE_A(kt_)  { OCHUNK(kt_,0,0); OCHUNK(kt_,0,64); OCHUNK(kt_,0,128); OCHUNK(kt_,0,192); }
#define OSTAGE_B(kt_)  { OCHUNK(kt_,1,0); OCHUNK(kt_,1,64); }

#define OR_A(mh_, lA_)                                                        \
  _Pragma("unroll") for (int st = 0; st < 4; ++st) {                          \
    int row = wr*64 + (mh_)*32 + l31;                                         \
    af[mh_][st] = *(const bf16x8*)((lA_) + row*128 + ((((st*2)+lh) ^ (row&7)) << 4)); }

#define OR_B(nh_, lB_)                                                        \
  _Pragma("unroll") for (int st = 0; st < 4; ++st) {                          \
    int row = wc*64 + (nh_)*32 + l31;                                         \
    bfr[nh_][st] = *(const bf16x8*)((lB_) + row*128 + ((((st*2)+lh) ^ (row&7)) << 4)); }

#define OMFMA(mh_, nh_, accv_)                                                \
  __builtin_amdgcn_s_setprio(1);                                              \
  _Pragma("unroll") for (int st = 0; st < 4; ++st)                            \
    accv_ = __builtin_amdgcn_mfma_f32_32x32x16_bf16(af[mh_][st], bfr[nh_][st], accv_, 0, 0, 0); \
  __builtin_amdgcn_s_setprio(0);

  OSTAGE_A(0); OSTAGE_B(0);
  OSTAGE_A(1); OSTAGE_B(1);
  asm volatile("s_waitcnt vmcnt(6)" ::: "memory");
  BAR; SCHB;
  {
    const char* lA0 = lds;
    const char* lB0 = lds + ABYT;
    OR_A(0, lA0); OR_B(0, lB0);
  }

  for (int kt = 0; kt < NK; ++kt) {
    const char* lA = lds + (kt&1)*STEP;
    const char* lB = lA + ABYT;
    OR_B(1, lB);
    asm volatile("s_waitcnt lgkmcnt(4)" ::: "memory");
    SCHB;
    OMFMA(0,0, acc00);
    OR_A(1, lA);
    asm volatile("s_waitcnt lgkmcnt(4)" ::: "memory");
    BAR; SCHB;
    if (kt+2 < NK) OSTAGE_B(kt+2);
    OMFMA(0,1, acc01);
    asm volatile("s_waitcnt lgkmcnt(0)" ::: "memory");
    BAR; SCHB;
    if (kt+2 < NK) OSTAGE_A(kt+2);
    OMFMA(1,0, acc10);
    if (kt+1 < NK) {
      if (kt+2 < NK) asm volatile("s_waitcnt vmcnt(6)" ::: "memory");
      else           asm volatile("s_waitcnt vmcnt(0)" ::: "memory");
      BAR; SCHB;
      const char* lAn = lds + ((kt+1)&1)*STEP;
      const char* lBn = lAn + ABYT;
      OR_A(0, lAn); OR_B(0, lBn);
      SCHB;
    }
    OMFMA(1,1, acc11);
  }
#undef OCHUNK
#undef OSTAGE_A
#undef OSTAGE_B
#undef OR_A
#undef OR_B
#undef OMFMA

#define OWRITE(mh_, nh_, accv_)                                               \
  _Pragma("unroll") for (int r = 0; r < 16; ++r) {                            \
    int row = m0 + wr*64 + (mh_)*32 + (r & 3) + 8*(r >> 2) + 4*lh;            \
    int col = n0 + wc*64 + (nh_)*32 + l31;                                    \
    C[(size_t)row * N + col] = accv_[r]; }
  OWRITE(0,0, acc00); OWRITE(0,1, acc01); OWRITE(1,0, acc10); OWRITE(1,1, acc11);
#undef OWRITE
}

// ---------------- causal GQA flash attention: block-cooperative LDS-staged K/V -------
__global__ __launch_bounds__(256, 4) void k_attn(
    const u16* __restrict__ Q, const u16* __restrict__ Kc,
    const u16* __restrict__ Vt, u16* __restrict__ AO)
{
  __shared__ __align__(16) char Kls[2][16384];
  __shared__ __align__(16) char Vls[2][16384];
  __shared__ u16 Pl[4][1024];

  int id = blockIdx.x;
  int slot = id >> 3;
  int bg   = (id & 7)*2 + (slot & 1);
  int rem  = slot >> 1;
  int h_in = rem & 3, bx = rem >> 2;
  int b = bg >> 3, g = bg & 7, h = g*4 + h_in;
  int tA = bx, tB = 15 - bx;

  int tid = threadIdx.x, w = tid >> 6, lane = tid & 63;
  int l15 = lane & 15, l4 = lane >> 4;
  const u16* Qh = Q  + ((size_t)b*H_   + h) * S_ * HD_;
  const u16* Kp = Kc + ((size_t)b*KVH_ + g) * S_ * HD_;
  const u16* Vp = Vt + ((size_t)b*KVH_ + g) * (size_t)HD_ * S_;
  u16* AOh = AO + ((size_t)b*S_) * (H_*HD_) + h*HD_;
  char* Pw = (char*)&Pl[w][0];

  int kOff[4], vOff[4];
#pragma unroll
  for (int c = 0; c < 4; ++c) {
    int ci = c*256 + tid;
    int krow = ci >> 4, ks = ci & 15;
    kOff[c] = krow * HD_ + ((ks & 8) | ((ks & 7) ^ (krow & 7))) * 8;
    int vrow = ci >> 3, vs = ci & 7;
    vOff[c] = vrow * S_ + (vs ^ (vrow & 7)) * 8;
  }

#define ASTAGE(kv_, bb_) {                                                    \
    const u16* ks_ = Kp + (size_t)(kv_) * 64 * HD_;                           \
    const u16* vs_ = Vp + (size_t)(kv_) * 64;                                 \
    _Pragma("unroll") for (int c = 0; c < 4; ++c) {                           \
      __builtin_amdgcn_global_load_lds((AS1 void*)(ks_ + kOff[c]),            \
          (AS3 void*)(&Kls[bb_][0] + c*4096 + w*1024), 16, 0, 0);             \
      __builtin_amdgcn_global_load_lds((AS1 void*)(vs_ + vOff[c]),            \
          (AS3 void*)(&Vls[bb_][0] + c*4096 + w*1024), 16, 0, 0); } }

  bf16x8 qf[4];
#pragma unroll
  for (int kc = 0; kc < 4; ++kc)
    qf[kc] = *(const bf16x8*)(Qh + (size_t)(tA*64 + w*16 + l15)*HD_ + kc*32 + l4*8);

  f32x4 o[8];
#pragma unroll
  for (int n = 0; n < 8; ++n) o[n] = (f32x4){0.f,0.f,0.f,0.f};
  float mrow[4] = {-3e38f,-3e38f,-3e38f,-3e38f};
  float lrow[4] = {0.f,0.f,0.f,0.f};

  ASTAGE(0, 0);
  asm volatile("s_waitcnt vmcnt(0)" ::: "memory");
  __builtin_amdgcn_s_barrier();

  const int NIT = tA + tB + 2;
  int buf = 0;
  for (int it = 0; it < NIT; ++it) {
    bool phA = (it <= tA);
    int kv = phA ? it : it - tA - 1;
    int qt = phA ? tA : tB;
    if (it + 1 < NIT) {
      int kvn = (it + 1 <= tA) ? it + 1 : it - tA;
      ASTAGE(kvn, buf ^ 1);
    }
    const char* Ksb = &Kls[buf][0];
    const char* Vsb = &Vls[buf][0];

    f32x4 sc[4];
    __builtin_amdgcn_s_setprio(1);
#pragma unroll
    for (int ct = 0; ct < 4; ++ct) {
      f32x4 s4 = (f32x4){0.f,0.f,0.f,0.f};
#pragma unroll
      for (int kc = 0; kc < 4; ++kc) {
        int row = ct*16 + l15, s = kc*4 + l4;
        bf16x8 kf = *(const bf16x8*)(Ksb + row*256 + ((((s & 7) ^ (row & 7)) | (s & 8)) << 4));
        s4 = __builtin_amdgcn_mfma_f32_16x16x32_bf16(qf[kc], kf, s4, 0, 0, 0);
      }
      sc[ct] = s4;
    }
    __builtin_amdgcn_s_setprio(0);

    if (kv == qt) {
      int qrow0 = qt*64 + w*16;
#pragma unroll
      for (int ct = 0; ct < 4; ++ct)
#pragma unroll
        for (int r = 0; r < 4; ++r) {
          int col = kv*64 + ct*16 + l15;
          if (col > qrow0 + l4*4 + r) sc[ct][r] = -1e9f;
        }
    }

    float f[4];
#pragma unroll
    for (int r = 0; r < 4; ++r) {
      float mx = fmaxf(fmaxf(sc[0][r], sc[1][r]), fmaxf(sc[2][r], sc[3][r]));
      mx = fmaxf(mx, __shfl_xor(mx, 1));
      mx = fmaxf(mx, __shfl_xor(mx, 2));
      mx = fmaxf(mx, __shfl_xor(mx, 4));
      mx = fmaxf(mx, __shfl_xor(mx, 8));
      float nm = fmaxf(mrow[r], mx);
      f[r] = __expf(mrow[r] - nm);
      mrow[r] = nm;
    }
    float rs[4] = {0.f,0.f,0.f,0.f};
#pragma unroll
    for (int ct = 0; ct < 4; ++ct)
#pragma unroll
      for (int r = 0; r < 4; ++r) {
        float p = __expf(sc[ct][r] - mrow[r]);
        rs[r] += p;
        int row = l4*4 + r, col = ct*16 + l15;
        int byte = row*128 + (((col >> 3) ^ (row & 7)) << 4) + (col & 7)*2;
        *(u16*)(Pw + byte) = f2bf(p);
      }
#pragma unroll
    for (int r = 0; r < 4; ++r) {
      float sum = rs[r];
      sum += __shfl_xor(sum, 1);
      sum += __shfl_xor(sum, 2);
      sum += __shfl_xor(sum, 4);
      sum += __shfl_xor(sum, 8);
      lrow[r] = lrow[r]*f[r] + sum;
    }
#pragma unroll
    for (int n = 0; n < 8; ++n)
#pragma unroll
      for (int r = 0; r < 4; ++r) o[n][r] *= f[r];

    __builtin_amdgcn_s_setprio(1);
#pragma unroll
    for (int kk = 0; kk < 2; ++kk) {
      int pbyte = l15*128 + (((kk*4 + l4) ^ (l15 & 7)) << 4);
      bf16x8 pf = *(const bf16x8*)(Pw + pbyte);
#pragma unroll
      for (int n = 0; n < 8; ++n) {
        int vrow = n*16 + l15, s = kk*4 + l4;
        bf16x8 vf = *(const bf16x8*)(Vsb + vrow*128 + ((s ^ (vrow & 7)) << 4));
        o[n] = __builtin_amdgcn_mfma_f32_16x16x32_bf16(pf, vf, o[n], 0, 0, 0);
      }
    }
    __builtin_amdgcn_s_setprio(0);

    if (it == tA) {
#pragma unroll
      for (int n = 0; n < 8; ++n)
#pragma unroll
        for (int r = 0; r < 4; ++r) {
          int srow = tA*64 + w*16 + l4*4 + r;
          AOh[(size_t)srow * (H_*HD_) + n*16 + l15] = f2bf(o[n][r] / lrow[r]);
        }
#pragma unroll
      for (int n = 0; n < 8; ++n) o[n] = (f32x4){0.f,0.f,0.f,0.f};
#pragma unroll
      for (int r = 0; r < 4; ++r) { mrow[r] = -3e38f; lrow[r] = 0.f; }
#pragma unroll
      for (int kc = 0; kc < 4; ++kc)
        qf[kc] = *(const bf16x8*)(Qh + (size_t)(tB*64 + w*16 + l15)*HD_ + kc*32 + l4*8);
    }

    asm volatile("s_waitcnt vmcnt(0)" ::: "memory");
    __builtin_amdgcn_s_barrier();
    buf ^= 1;
  }
#undef ASTAGE

#pragma unroll
  for (int n = 0; n < 8; ++n)
#pragma unroll
    for (int r = 0; r < 4; ++r) {
      int srow = tB*64 + w*16 + l4*4 + r;
      AOh[(size_t)srow * (H_*HD_) + n*16 + l15] = f2bf(o[n][r] / lrow[r]);
    }
}

extern "C" void kernel_launch(void* const* d_in, const int* in_sizes, int n_in,
                              void* d_out, int out_size, void* d_ws, size_t ws_size,
                              hipStream_t stream) {
  (void)in_sizes; (void)n_in; (void)out_size; (void)ws_size;
  const float* x   = (const float*)d_in[0];
  const int*   sid = (const int*)  d_in[1];
  // d_in[2] = cache (dead), d_in[3] = mask (dead: causal re-derived)
  const float* Wq  = (const float*)d_in[4];
  const float* bq  = (const float*)d_in[5];
  const float* Wk  = (const float*)d_in[6];
  const float* bk  = (const float*)d_in[7];
  const float* Wv  = (const float*)d_in[8];
  const float* bv  = (const float*)d_in[9];
  const float* Wo  = (const float*)d_in[10];
  float* out = (float*)d_out;

  char* ws = (char*)d_ws;
  u16*   xb   = (u16*)  (ws);                    // 16 MB (aliased by AO later)
  u16*   WB   = (u16*)  (ws + 16777216);         // 48 MB  [6144][4096] (Q/K cols permuted)
  u16*   WoT  = (u16*)  (ws + 67108864);         // 32 MB  [4096][4096]
  u16*   qb   = (u16*)  (ws + 150994944);        // 16 MB  [B][H][S][HD]
  u16*   kb   = (u16*)  (ws + 167772160);        //  4 MB  [B][KVH][S][HD]
  u16*   VT   = (u16*)  (ws + 176160768);        //  4 MB  [B][KVH][HD][S]
  float* cosd = (float*)(ws + 180355072);        // 256 KB
  float* sind = (float*)(ws + 180617216);        // 256 KB
  u16*   AO   = xb;                              // attention output reuses xb

  k_prep<<<18688, 256, 0, stream>>>(x, xb, Wq, Wk, Wv, Wo, WB, WoT, sid, cosd, sind);
  k_gemmq<<<256, 512, 0, stream>>>(xb, WB, bq, bk, bv, cosd, sind, qb, kb, VT);
  k_attn<<<512, 256, 0, stream>>>(qb, kb, VT, AO);
  k_gemmo<<<256, 512, 0, stream>>>(AO, WoT, out, 4096, 4096);
}